// Round 7
// baseline (226.220 us; speedup 1.0000x reference)
//
#include <hip/hip_runtime.h>

typedef __bf16 bf16x8 __attribute__((ext_vector_type(8)));
typedef float f32x4 __attribute__((ext_vector_type(4)));
typedef float f32x16 __attribute__((ext_vector_type(16)));
typedef unsigned short u16;
typedef unsigned int u32;
typedef unsigned long long u64;

#define BB 4
#define NNCTX 2048
#define CCH 384
#define NHEAD 6
#define DHEAD 64
#define HIDDIM 1536

__device__ __forceinline__ u16 f2bf(float f){
  u32 u = __builtin_bit_cast(u32, f);
  u = u + 0x7fffu + ((u >> 16) & 1u);
  return (u16)(u >> 16);
}
__device__ __forceinline__ float bf2f(u16 h){
  u32 u = ((u32)h) << 16;
  return __builtin_bit_cast(float, u);
}

union U8 { uint4 u; u16 s[8]; bf16x8 v; };
union F8 { u32 w[4]; bf16x8 v; };

// Cast + TRANSPOSE all 4 weights to bf16 [N][K] (k-contiguous) via LDS-tiled 64x64 transpose.
__global__ __launch_bounds__(256) void cast_tr(const float* __restrict__ w0, const float* __restrict__ w1,
    const float* __restrict__ w2, const float* __restrict__ w3,
    u16* __restrict__ o0, u16* __restrict__ o1, u16* __restrict__ o2, u16* __restrict__ o3){
  __shared__ float S[64][65];
  int idx = blockIdx.x;
  const float* src; u16* dst; int K, N, kt, nt;
  if (idx < 108){ src = w0; dst = o0; K = 384; N = 1152; kt = idx / 18; nt = idx % 18; }
  else if (idx < 144){ idx -= 108; src = w1; dst = o1; K = 384; N = 384; kt = idx / 6; nt = idx % 6; }
  else if (idx < 288){ idx -= 144; src = w2; dst = o2; K = 384; N = 1536; kt = idx / 24; nt = idx % 24; }
  else { idx -= 288; src = w3; dst = o3; K = 1536; N = 384; kt = idx / 6; nt = idx % 6; }
  int t = threadIdx.x;
  int r4 = t >> 6, c = t & 63;
  int k0 = kt * 64, n0 = nt * 64;
  #pragma unroll
  for (int i = 0; i < 16; i++){
    int row = i * 4 + r4;
    S[row][c] = src[(size_t)(k0 + row) * N + n0 + c];
  }
  __syncthreads();
  #pragma unroll
  for (int i = 0; i < 16; i++){
    int row = i * 4 + r4;
    dst[(size_t)(n0 + row) * K + k0 + c] = f2bf(S[c][row]);
  }
}

// One block per row (C=384), 128 threads.
__global__ __launch_bounds__(128) void ln_kernel(const float* __restrict__ x, const float* __restrict__ g,
                                                 const float* __restrict__ bb, u16* __restrict__ out){
  int row = blockIdx.x, t = threadIdx.x;
  const float* xr = x + (size_t)row * CCH;
  float v0 = xr[t], v1 = xr[t + 128], v2 = xr[t + 256];
  float s = v0 + v1 + v2;
  float q = v0 * v0 + v1 * v1 + v2 * v2;
  #pragma unroll
  for (int o = 32; o; o >>= 1){ s += __shfl_down(s, o); q += __shfl_down(q, o); }
  __shared__ float sh[4];
  if ((t & 63) == 0){ int w = t >> 6; sh[w * 2] = s; sh[w * 2 + 1] = q; }
  __syncthreads();
  float sum = sh[0] + sh[2], ssq = sh[1] + sh[3];
  float mu = sum * (1.0f / 384.0f);
  float rstd = rsqrtf(ssq * (1.0f / 384.0f) - mu * mu + 1e-5f);
  size_t base = (size_t)row * CCH;
  out[base + t]       = f2bf((v0 - mu) * rstd * g[t]       + bb[t]);
  out[base + t + 128] = f2bf((v1 - mu) * rstd * g[t + 128] + bb[t + 128]);
  out[base + t + 256] = f2bf((v2 - mu) * rstd * g[t + 256] + bb[t + 256]);
}

// 64x64-tile GEMM (proj / fc2): C = A @ Bt^T, Bt is [Nn][K]. EPI 1: fp32 out = resid+acc+bias.
template<int EPI, int DBUF>
__global__ __launch_bounds__(256) void gemm_bf16(const u16* __restrict__ A, const u16* __restrict__ Bt,
    int K, int Nn, u16* __restrict__ outb, const float* __restrict__ bias,
    const float* __restrict__ resid, float* __restrict__ outf)
{
  __shared__ u16 As[DBUF + 1][64][68];
  __shared__ u16 Bs[DBUF + 1][64][68];
  int t = threadIdx.x;
  int bm = blockIdx.y * 64, bn = blockIdx.x * 64;
  int l = t & 63, w = t >> 6;
  int wm = (w >> 1) * 32, wn = (w & 1) * 32;
  f32x4 acc[2][2] = {};
  int ar0 = t >> 3, ac0 = (t & 7) * 8;
  uint4 la0, la1, lb0, lb1;
  auto LOADG = [&](int k0){
    la0 = *(const uint4*)&A[(size_t)(bm + ar0) * K + k0 + ac0];
    la1 = *(const uint4*)&A[(size_t)(bm + ar0 + 32) * K + k0 + ac0];
    lb0 = *(const uint4*)&Bt[(size_t)(bn + ar0) * K + k0 + ac0];
    lb1 = *(const uint4*)&Bt[(size_t)(bn + ar0 + 32) * K + k0 + ac0];
  };
  auto WRITEL = [&](int bf){
    *(uint4*)&As[bf][ar0][ac0]      = la0;
    *(uint4*)&As[bf][ar0 + 32][ac0] = la1;
    *(uint4*)&Bs[bf][ar0][ac0]      = lb0;
    *(uint4*)&Bs[bf][ar0 + 32][ac0] = lb1;
  };
  auto COMPUTE = [&](int bf){
    #pragma unroll
    for (int ks = 0; ks < 2; ks++){
      int kb = ks * 32 + (l >> 4) * 8;
      bf16x8 a0  = *(const bf16x8*)&As[bf][wm + (l & 15)][kb];
      bf16x8 a1  = *(const bf16x8*)&As[bf][wm + 16 + (l & 15)][kb];
      bf16x8 bb0 = *(const bf16x8*)&Bs[bf][wn + (l & 15)][kb];
      bf16x8 bb1 = *(const bf16x8*)&Bs[bf][wn + 16 + (l & 15)][kb];
      acc[0][0] = __builtin_amdgcn_mfma_f32_16x16x32_bf16(a0, bb0, acc[0][0], 0, 0, 0);
      acc[0][1] = __builtin_amdgcn_mfma_f32_16x16x32_bf16(a0, bb1, acc[0][1], 0, 0, 0);
      acc[1][0] = __builtin_amdgcn_mfma_f32_16x16x32_bf16(a1, bb0, acc[1][0], 0, 0, 0);
      acc[1][1] = __builtin_amdgcn_mfma_f32_16x16x32_bf16(a1, bb1, acc[1][1], 0, 0, 0);
    }
  };
  if constexpr (DBUF){
    int nk = K >> 6;
    LOADG(0);
    WRITEL(0);
    __syncthreads();
    for (int ki = 0; ki < nk; ki++){
      int cur = ki & 1;
      if (ki + 1 < nk) LOADG((ki + 1) << 6);
      COMPUTE(cur);
      if (ki + 1 < nk) WRITEL(cur ^ 1);
      __syncthreads();
    }
  } else {
    for (int k0 = 0; k0 < K; k0 += 64){
      __syncthreads();
      LOADG(k0);
      WRITEL(0);
      __syncthreads();
      COMPUTE(0);
    }
  }
  #pragma unroll
  for (int mi = 0; mi < 2; mi++)
  #pragma unroll
  for (int ni = 0; ni < 2; ni++)
  #pragma unroll
  for (int r = 0; r < 4; r++){
    int row = bm + wm + mi * 16 + ((l >> 4) << 2) + r;
    int col = bn + wn + ni * 16 + (l & 15);
    size_t idx = (size_t)row * Nn + col;
    float v = acc[mi][ni][r];
    if (EPI == 0){
      outb[idx] = f2bf(v);
    } else if (EPI == 1){
      outf[idx] = resid[idx] + v + bias[col];
    } else {
      v += bias[col];
      v = 0.5f * v * (1.0f + erff(v * 0.70710678118f));
      outb[idx] = f2bf(v);
    }
  }
}

// 128x64-tile GEMM (qkv / fc1): 4 waves, each 64x32 out (4x2 of 16x16). Single-LDS + reg prefetch.
// EPI 0: bf16 store. EPI 2: bf16 gelu(acc+bias).
template<int EPI>
__global__ __launch_bounds__(256) void gemm128(const u16* __restrict__ A, const u16* __restrict__ Bt,
    int K, int Nn, u16* __restrict__ outb, const float* __restrict__ bias)
{
  __shared__ u16 As[128][68];
  __shared__ u16 Bs[64][68];
  int t = threadIdx.x;
  int bm = blockIdx.y * 128, bn = blockIdx.x * 64;
  int l = t & 63, w = t >> 6;
  int wm = (w >> 1) * 64, wn = (w & 1) * 32;
  int lr = l & 15, lg4 = l >> 4;
  f32x4 acc[4][2] = {};
  int ar0 = t >> 3, ac0 = (t & 7) * 8;
  uint4 la[4], lb[2];
  auto LOADG = [&](int k0){
    #pragma unroll
    for (int i = 0; i < 4; i++)
      la[i] = *(const uint4*)&A[(size_t)(bm + ar0 + i * 32) * K + k0 + ac0];
    #pragma unroll
    for (int i = 0; i < 2; i++)
      lb[i] = *(const uint4*)&Bt[(size_t)(bn + ar0 + i * 32) * K + k0 + ac0];
  };
  auto WRITEL = [&](){
    #pragma unroll
    for (int i = 0; i < 4; i++) *(uint4*)&As[ar0 + i * 32][ac0] = la[i];
    #pragma unroll
    for (int i = 0; i < 2; i++) *(uint4*)&Bs[ar0 + i * 32][ac0] = lb[i];
  };
  auto COMPUTE = [&](){
    #pragma unroll
    for (int ks = 0; ks < 2; ks++){
      int kb = ks * 32 + lg4 * 8;
      bf16x8 bb0 = *(const bf16x8*)&Bs[wn + lr][kb];
      bf16x8 bb1 = *(const bf16x8*)&Bs[wn + 16 + lr][kb];
      #pragma unroll
      for (int mi = 0; mi < 4; mi++){
        bf16x8 am = *(const bf16x8*)&As[wm + mi * 16 + lr][kb];
        acc[mi][0] = __builtin_amdgcn_mfma_f32_16x16x32_bf16(am, bb0, acc[mi][0], 0, 0, 0);
        acc[mi][1] = __builtin_amdgcn_mfma_f32_16x16x32_bf16(am, bb1, acc[mi][1], 0, 0, 0);
      }
    }
  };
  int nk = K >> 6;
  LOADG(0);
  WRITEL();
  __syncthreads();
  for (int ki = 0; ki < nk; ki++){
    if (ki + 1 < nk) LOADG((ki + 1) << 6);
    COMPUTE();
    __syncthreads();
    if (ki + 1 < nk) WRITEL();
    __syncthreads();
  }
  #pragma unroll
  for (int mi = 0; mi < 4; mi++)
  #pragma unroll
  for (int ni = 0; ni < 2; ni++)
  #pragma unroll
  for (int r = 0; r < 4; r++){
    int row = bm + wm + mi * 16 + (l >> 4) * 4 + r;
    int col = bn + wn + ni * 16 + lr;
    size_t idx = (size_t)row * Nn + col;
    float v = acc[mi][ni][r];
    if (EPI == 0){
      outb[idx] = f2bf(v);
    } else {
      v += bias[col];
      v = 0.5f * v * (1.0f + erff(v * 0.70710678118f));
      outb[idx] = f2bf(v);
    }
  }
}

// One PV k-step (16 keys): build PA frag in-register (cvt_pk + permlane32_swap), tr-read V, 3 MFMA.
#define PVSTEP(O0, O1, O2, O3, SX, BASE)                                         \
  {                                                                              \
    float p0 = __builtin_exp2f(SX[BASE + 0] - m_q);                              \
    float p1 = __builtin_exp2f(SX[BASE + 1] - m_q);                              \
    float p2 = __builtin_exp2f(SX[BASE + 2] - m_q);                              \
    float p3 = __builtin_exp2f(SX[BASE + 3] - m_q);                              \
    float p4 = __builtin_exp2f(SX[BASE + 4] - m_q);                              \
    float p5 = __builtin_exp2f(SX[BASE + 5] - m_q);                              \
    float p6 = __builtin_exp2f(SX[BASE + 6] - m_q);                              \
    float p7 = __builtin_exp2f(SX[BASE + 7] - m_q);                              \
    u32 wa0, wa1, wb0, wb1;                                                      \
    asm("v_cvt_pk_bf16_f32 %0, %1, %2" : "=v"(wa0) : "v"(p0), "v"(p1));          \
    asm("v_cvt_pk_bf16_f32 %0, %1, %2" : "=v"(wa1) : "v"(p2), "v"(p3));          \
    asm("v_cvt_pk_bf16_f32 %0, %1, %2" : "=v"(wb0) : "v"(p4), "v"(p5));          \
    asm("v_cvt_pk_bf16_f32 %0, %1, %2" : "=v"(wb1) : "v"(p6), "v"(p7));          \
    asm("v_permlane32_swap_b32 %0, %1" : "+v"(wa0), "+v"(wb0));                  \
    asm("v_permlane32_swap_b32 %0, %1" : "+v"(wa1), "+v"(wb1));                  \
    F8 pa; pa.w[0] = wa0; pa.w[1] = wa1; pa.w[2] = wb0; pa.w[3] = wb1;           \
    u64 ta, tb, tc, td;                                                          \
    asm volatile("ds_read_b64_tr_b16 %0, %4 offset:" #O0 "\n\t"                  \
                 "ds_read_b64_tr_b16 %1, %4 offset:" #O1 "\n\t"                  \
                 "ds_read_b64_tr_b16 %2, %4 offset:" #O2 "\n\t"                  \
                 "ds_read_b64_tr_b16 %3, %4 offset:" #O3 "\n\t"                  \
                 "s_waitcnt lgkmcnt(0)"                                          \
                 : "=&v"(ta), "=&v"(tb), "=&v"(tc), "=&v"(td)                    \
                 : "v"(vtr));                                                    \
    __builtin_amdgcn_sched_barrier(0);                                           \
    F8 f0, f1;                                                                   \
    f0.w[0] = (u32)ta; f0.w[1] = (u32)(ta >> 32);                                \
    f0.w[2] = (u32)tb; f0.w[3] = (u32)(tb >> 32);                                \
    f1.w[0] = (u32)tc; f1.w[1] = (u32)(tc >> 32);                                \
    f1.w[2] = (u32)td; f1.w[3] = (u32)(td >> 32);                                \
    l_acc = __builtin_amdgcn_mfma_f32_32x32x16_bf16(pa.v, onesf, l_acc, 0, 0, 0);\
    o_0 = __builtin_amdgcn_mfma_f32_32x32x16_bf16(pa.v, f0.v, o_0, 0, 0, 0);     \
    o_1 = __builtin_amdgcn_mfma_f32_32x32x16_bf16(pa.v, f1.v, o_1, 0, 0, 0);     \
  }

// MFMA flash attention: swapped QK^T (S^T = K Q^T) -> in-register softmax, no P LDS.
// Block = 256 thr (4 waves), q-tile 128 (32 q/wave), KV tile 64, KV-split 2, XCD-pinned.
// Lane holds P[32 keys] for q = lane&31 (S-form); O/l accumulate in C-form [16 q rows][d col].
// PA MFMA A-frags built via v_cvt_pk_bf16_f32 + v_permlane32_swap_b32.
__global__ __launch_bounds__(256, 3) void attn_mfma(const u16* __restrict__ qkv,
    u16* __restrict__ o0buf, u16* __restrict__ o1buf, float2* __restrict__ mlbuf){
  __shared__ u16 Ks[64][68];                               // [key][d]
  __shared__ __attribute__((aligned(128))) u16 Vs[4096];   // [key>>2][dblk][4][16] subtiled, natural order
  int t = threadIdx.x;
  int w = t >> 6, l = t & 63;
  int c31 = l & 31, hi = l >> 5, hi8 = hi * 8;
  // XCD-pinned decode: 768 blocks = 48 groups x 16 q-blocks; group pinned to id&7.
  int id = blockIdx.x;
  int xcd = id & 7, slot = id >> 3;
  int qb = slot & 15;
  int group = (slot >> 4) * 8 + xcd;
  int bh = group % (BB * NHEAD);
  int sp = group / (BB * NHEAD);
  int b = bh / NHEAD, h = bh % NHEAD;
  int q0 = qb * 128;

  const float QS = 0.1803368801111716f;                    // 0.125 * log2(e)
  bf16x8 qf[4];                                            // Q[q=c31][k-chunk c: d = c*16+hi8+j]
  {
    const u16* qp = qkv + (size_t)(b * NNCTX + q0 + w * 32 + c31) * 1152 + h * 64 + hi8;
    #pragma unroll
    for (int c = 0; c < 4; c++){
      U8 r; r.u = *(const uint4*)(qp + c * 16);
      #pragma unroll
      for (int j = 0; j < 8; j++) r.s[j] = f2bf(bf2f(r.s[j]) * QS);
      qf[c] = r.v;
    }
  }
  bf16x8 onesf;
  {
    U8 r;
    #pragma unroll
    for (int j = 0; j < 8; j++) r.s[j] = 0x3F80;
    onesf = r.v;
  }
  f32x16 o_0 = {}, o_1 = {};
  f32x16 l_acc = {};
  float m_q = -3.4e38f;

  const size_t kvrow = (size_t)(b * NNCTX) * 1152 + h * 64;
  int kkey = t >> 2, kdp = (t & 3) * 16;
  int vkey = t & 63, vdblk = w * 16;
  int voff = (vkey >> 2) * 256 + w * 64 + (vkey & 3) * 16;  // u16 units, natural key order
  int lg = l >> 4, lr16 = l & 15;
  u32 vtr = (u32)(uintptr_t)(&Vs[0]) + (u32)((lg >> 1) * 1024 + (lg & 1) * 128 + lr16 * 8);

  uint4 kra, krb, vra, vrb;
  auto LOADT = [&](int kt){
    const u16* kp = qkv + kvrow + (size_t)(kt * 64 + kkey) * 1152 + 384 + kdp;
    kra = *(const uint4*)kp;
    krb = *(const uint4*)(kp + 8);
    const u16* vp = qkv + kvrow + (size_t)(kt * 64 + vkey) * 1152 + 768 + vdblk;
    vra = *(const uint4*)vp;
    vrb = *(const uint4*)(vp + 8);
  };
  auto WRITET = [&](){
    *(uint4*)&Ks[kkey][kdp]     = kra;
    *(uint4*)&Ks[kkey][kdp + 8] = krb;
    *(uint4*)&Vs[voff]     = vra;
    *(uint4*)&Vs[voff + 8] = vrb;
  };

  int ktbeg = sp * 16, ktend = ktbeg + 16;
  LOADT(ktbeg);
  WRITET();
  __syncthreads();

  for (int kt = ktbeg; kt < ktend; kt++){
    if (kt + 1 < ktend) LOADT(kt + 1);

    // S^T = K Q^T: lane holds S[key crow(r,hi)][q=c31]; s0 keys 0-31, s1 keys 32-63
    f32x16 s0 = {}, s1 = {};
    #pragma unroll
    for (int c = 0; c < 4; c++){
      bf16x8 kf0 = *(const bf16x8*)&Ks[c31][c * 16 + hi8];
      bf16x8 kf1 = *(const bf16x8*)&Ks[32 + c31][c * 16 + hi8];
      s0 = __builtin_amdgcn_mfma_f32_32x32x16_bf16(kf0, qf[c], s0, 0, 0, 0);
      s1 = __builtin_amdgcn_mfma_f32_32x32x16_bf16(kf1, qf[c], s1, 0, 0, 0);
    }
    // per-q max: 31 lane-local fmax + partner exchange
    float px = fmaxf(s0[0], s0[1]);
    #pragma unroll
    for (int r = 2; r < 16; r++) px = fmaxf(px, s0[r]);
    #pragma unroll
    for (int r = 0; r < 16; r++) px = fmaxf(px, s1[r]);
    px = fmaxf(px, __shfl_xor(px, 32));
    // defer-max THR=8 (exp2 domain)
    if (!__all(px <= m_q + 8.f)){
      float mn = fmaxf(m_q, px);
      float a = __builtin_exp2f(m_q - mn);
      m_q = mn;
      #pragma unroll
      for (int r = 0; r < 16; r++){
        int cr = (r & 3) + 8 * (r >> 2) + 4 * hi;
        float ar = __shfl(a, cr);
        o_0[r] *= ar; o_1[r] *= ar; l_acc[r] *= ar;
      }
    }
    // PV: 4 k-steps of 16 keys
    PVSTEP(0, 512, 256, 768, s0, 0)
    PVSTEP(2048, 2560, 2304, 2816, s0, 8)
    PVSTEP(4096, 4608, 4352, 4864, s1, 0)
    PVSTEP(6144, 6656, 6400, 6912, s1, 8)

    __syncthreads();
    if (kt + 1 < ktend) WRITET();
    __syncthreads();
  }
  // epilogue: unnormalized O + (m, l); m gathered from S-form via shfl
  u16* obuf = sp ? o1buf : o0buf;
  #pragma unroll
  for (int r = 0; r < 16; r++){
    int cr = (r & 3) + 8 * (r >> 2) + 4 * hi;
    float mr = __shfl(m_q, cr);
    int n = q0 + w * 32 + cr;
    size_t row = (size_t)(b * NNCTX + n);
    u16* op = obuf + row * CCH + h * 64;
    op[c31]      = f2bf(o_0[r]);
    op[32 + c31] = f2bf(o_1[r]);
    if (c31 == 0)
      mlbuf[((size_t)(sp * BB * NHEAD + bh)) * NNCTX + n] = make_float2(mr, l_acc[r]);
  }
}

// Merge the two KV-splits.
__global__ __launch_bounds__(128) void attn_combine(const u16* __restrict__ o0, const u16* __restrict__ o1,
    const float2* __restrict__ ml, u16* __restrict__ obuf){
  __shared__ float sc0[NHEAD], sc1[NHEAD];
  int row = blockIdx.x;
  int b = row >> 11, n = row & 2047;
  int t = threadIdx.x;
  if (t < NHEAD){
    float2 a = ml[(size_t)(b * NHEAD + t) * NNCTX + n];
    float2 c = ml[(size_t)(BB * NHEAD + b * NHEAD + t) * NNCTX + n];
    float M = fmaxf(a.x, c.x);
    float e0 = exp2f(a.x - M), e1 = exp2f(c.x - M);
    float inv = 1.0f / (a.y * e0 + c.y * e1);
    sc0[t] = e0 * inv; sc1[t] = e1 * inv;
  }
  __syncthreads();
  size_t base = (size_t)row * CCH;
  #pragma unroll
  for (int i = 0; i < 3; i++){
    int c = t + i * 128;
    int h = c >> 6;
    float v = bf2f(o0[base + c]) * sc0[h] + bf2f(o1[base + c]) * sc1[h];
    obuf[base + c] = f2bf(v);
  }
}

extern "C" void kernel_launch(void* const* d_in, const int* in_sizes, int n_in,
                              void* d_out, int out_size, void* d_ws, size_t ws_size,
                              hipStream_t stream){
  const float* x      = (const float*)d_in[0];
  const float* ln1_g  = (const float*)d_in[1];
  const float* ln1_b  = (const float*)d_in[2];
  const float* w_qkv  = (const float*)d_in[3];
  const float* w_proj = (const float*)d_in[4];
  const float* b_proj = (const float*)d_in[5];
  const float* ln2_g  = (const float*)d_in[6];
  const float* ln2_b  = (const float*)d_in[7];
  const float* w_fc1  = (const float*)d_in[8];
  const float* b_fc1  = (const float*)d_in[9];
  const float* w_fc2  = (const float*)d_in[10];
  const float* b_fc2  = (const float*)d_in[11];
  float* out = (float*)d_out;

  u16* ws = (u16*)d_ws;
  u16* wqkv_bf  = ws;                       // [1152][384] transposed
  u16* wproj_bf = wqkv_bf + 442368;         // [384][384]
  u16* wfc1_bf  = wproj_bf + 147456;        // [1536][384]
  u16* wfc2_bf  = wfc1_bf + 589824;         // [384][1536]
  u16* h_bf     = wfc2_bf + 589824;         // 8192*384 (LN out; reused as opart0, then h2)
  u16* qkv_bf   = h_bf + 3145728;           // 8192*1152
  u16* o_bf     = qkv_bf + 9437184;         // 8192*384 (combined attention out)
  u16* opart1   = o_bf + 3145728;           // 8192*384
  float2* mlbuf = (float2*)(opart1 + 3145728); // [2][B*H][N]
  u16* opart0   = h_bf;
  u16* m_bf     = qkv_bf;                   // 8192*1536 (reuses qkv+o after proj)

  cast_tr<<<432, 256, 0, stream>>>(w_qkv, w_proj, w_fc1, w_fc2, wqkv_bf, wproj_bf, wfc1_bf, wfc2_bf);

  // LN1 -> h (bf16)
  ln_kernel<<<8192, 128, 0, stream>>>(x, ln1_g, ln1_b, h_bf);
  // QKV = h @ w_qkv
  gemm128<0><<<dim3(18, 64), 256, 0, stream>>>(h_bf, wqkv_bf, 384, 1152, qkv_bf, nullptr);
  // attention (KV-split 2, XCD-pinned, in-register softmax) -> partial O + (m,l)
  attn_mfma<<<dim3(768), 256, 0, stream>>>(qkv_bf, opart0, opart1, mlbuf);
  // combine splits -> o (bf16)
  attn_combine<<<8192, 128, 0, stream>>>(opart0, opart1, mlbuf, o_bf);
  // x1 = x + o @ w_proj + b_proj
  gemm_bf16<1, 1><<<dim3(6, 128), 256, 0, stream>>>(o_bf, wproj_bf, 384, 384, nullptr, b_proj, x, out);
  // LN2 -> h2
  ln_kernel<<<8192, 128, 0, stream>>>(out, ln2_g, ln2_b, h_bf);
  // m = gelu(h2 @ w_fc1 + b_fc1)
  gemm128<2><<<dim3(24, 64), 256, 0, stream>>>(h_bf, wfc1_bf, 384, 1536, m_bf, b_fc1);
  // out = x1 + m @ w_fc2 + b_fc2
  gemm_bf16<1, 1><<<dim3(6, 128), 256, 0, stream>>>(m_bf, wfc2_bf, 1536, 384, nullptr, b_fc2, out, out);
}

// Round 8
// 153.303 us; speedup vs baseline: 1.4756x; 1.4756x over previous
//
#include <hip/hip_runtime.h>

typedef __bf16 bf16x8 __attribute__((ext_vector_type(8)));
typedef float f32x4 __attribute__((ext_vector_type(4)));
typedef float f32x16 __attribute__((ext_vector_type(16)));
typedef unsigned short u16;
typedef unsigned int u32;
typedef unsigned long long u64;

#define BB 4
#define NNCTX 2048
#define CCH 384
#define NHEAD 6
#define DHEAD 64
#define HIDDIM 1536

__device__ __forceinline__ u16 f2bf(float f){
  u32 u = __builtin_bit_cast(u32, f);
  u = u + 0x7fffu + ((u >> 16) & 1u);
  return (u16)(u >> 16);
}
__device__ __forceinline__ float bf2f(u16 h){
  u32 u = ((u32)h) << 16;
  return __builtin_bit_cast(float, u);
}

union U8 { uint4 u; u16 s[8]; bf16x8 v; };
union F8 { u32 w[4]; bf16x8 v; };

// Cast + TRANSPOSE all 4 weights to bf16 [N][K] (k-contiguous) via LDS-tiled 64x64 transpose.
__global__ __launch_bounds__(256) void cast_tr(const float* __restrict__ w0, const float* __restrict__ w1,
    const float* __restrict__ w2, const float* __restrict__ w3,
    u16* __restrict__ o0, u16* __restrict__ o1, u16* __restrict__ o2, u16* __restrict__ o3){
  __shared__ float S[64][65];
  int idx = blockIdx.x;
  const float* src; u16* dst; int K, N, kt, nt;
  if (idx < 108){ src = w0; dst = o0; K = 384; N = 1152; kt = idx / 18; nt = idx % 18; }
  else if (idx < 144){ idx -= 108; src = w1; dst = o1; K = 384; N = 384; kt = idx / 6; nt = idx % 6; }
  else if (idx < 288){ idx -= 144; src = w2; dst = o2; K = 384; N = 1536; kt = idx / 24; nt = idx % 24; }
  else { idx -= 288; src = w3; dst = o3; K = 1536; N = 384; kt = idx / 6; nt = idx % 6; }
  int t = threadIdx.x;
  int r4 = t >> 6, c = t & 63;
  int k0 = kt * 64, n0 = nt * 64;
  #pragma unroll
  for (int i = 0; i < 16; i++){
    int row = i * 4 + r4;
    S[row][c] = src[(size_t)(k0 + row) * N + n0 + c];
  }
  __syncthreads();
  #pragma unroll
  for (int i = 0; i < 16; i++){
    int row = i * 4 + r4;
    dst[(size_t)(n0 + row) * K + k0 + c] = f2bf(S[c][row]);
  }
}

// One block per row (C=384), 128 threads.
__global__ __launch_bounds__(128) void ln_kernel(const float* __restrict__ x, const float* __restrict__ g,
                                                 const float* __restrict__ bb, u16* __restrict__ out){
  int row = blockIdx.x, t = threadIdx.x;
  const float* xr = x + (size_t)row * CCH;
  float v0 = xr[t], v1 = xr[t + 128], v2 = xr[t + 256];
  float s = v0 + v1 + v2;
  float q = v0 * v0 + v1 * v1 + v2 * v2;
  #pragma unroll
  for (int o = 32; o; o >>= 1){ s += __shfl_down(s, o); q += __shfl_down(q, o); }
  __shared__ float sh[4];
  if ((t & 63) == 0){ int w = t >> 6; sh[w * 2] = s; sh[w * 2 + 1] = q; }
  __syncthreads();
  float sum = sh[0] + sh[2], ssq = sh[1] + sh[3];
  float mu = sum * (1.0f / 384.0f);
  float rstd = rsqrtf(ssq * (1.0f / 384.0f) - mu * mu + 1e-5f);
  size_t base = (size_t)row * CCH;
  out[base + t]       = f2bf((v0 - mu) * rstd * g[t]       + bb[t]);
  out[base + t + 128] = f2bf((v1 - mu) * rstd * g[t + 128] + bb[t + 128]);
  out[base + t + 256] = f2bf((v2 - mu) * rstd * g[t + 256] + bb[t + 256]);
}

// 64x64-tile GEMM: C = A @ Bt^T, Bt is [Nn][K] k-contiguous (pre-transposed).
// 256 threads (4 waves, 2x2 of 32x32 out). 8 blocks/CU -> TLP hides staging latency.
// EPI 0: bf16 store (LDS-staged, coalesced 128B lines). EPI 1: fp32 out = resid + acc + bias.
// EPI 2: bf16 gelu(acc+bias) (LDS-staged). DBUF 1: dbuf + reg prefetch for grid-limited launches.
template<int EPI, int DBUF>
__global__ __launch_bounds__(256) void gemm_bf16(const u16* __restrict__ A, const u16* __restrict__ Bt,
    int K, int Nn, u16* __restrict__ outb, const float* __restrict__ bias,
    const float* __restrict__ resid, float* __restrict__ outf)
{
  __shared__ u16 As[DBUF + 1][64][68];
  __shared__ u16 Bs[DBUF + 1][64][68];
  int t = threadIdx.x;
  int bm = blockIdx.y * 64, bn = blockIdx.x * 64;
  int l = t & 63, w = t >> 6;
  int wm = (w >> 1) * 32, wn = (w & 1) * 32;
  f32x4 acc[2][2] = {};
  int ar0 = t >> 3, ac0 = (t & 7) * 8;
  uint4 la0, la1, lb0, lb1;
  auto LOADG = [&](int k0){
    la0 = *(const uint4*)&A[(size_t)(bm + ar0) * K + k0 + ac0];
    la1 = *(const uint4*)&A[(size_t)(bm + ar0 + 32) * K + k0 + ac0];
    lb0 = *(const uint4*)&Bt[(size_t)(bn + ar0) * K + k0 + ac0];
    lb1 = *(const uint4*)&Bt[(size_t)(bn + ar0 + 32) * K + k0 + ac0];
  };
  auto WRITEL = [&](int bf){
    *(uint4*)&As[bf][ar0][ac0]      = la0;
    *(uint4*)&As[bf][ar0 + 32][ac0] = la1;
    *(uint4*)&Bs[bf][ar0][ac0]      = lb0;
    *(uint4*)&Bs[bf][ar0 + 32][ac0] = lb1;
  };
  auto COMPUTE = [&](int bf){
    #pragma unroll
    for (int ks = 0; ks < 2; ks++){
      int kb = ks * 32 + (l >> 4) * 8;
      bf16x8 a0  = *(const bf16x8*)&As[bf][wm + (l & 15)][kb];
      bf16x8 a1  = *(const bf16x8*)&As[bf][wm + 16 + (l & 15)][kb];
      bf16x8 bb0 = *(const bf16x8*)&Bs[bf][wn + (l & 15)][kb];
      bf16x8 bb1 = *(const bf16x8*)&Bs[bf][wn + 16 + (l & 15)][kb];
      acc[0][0] = __builtin_amdgcn_mfma_f32_16x16x32_bf16(a0, bb0, acc[0][0], 0, 0, 0);
      acc[0][1] = __builtin_amdgcn_mfma_f32_16x16x32_bf16(a0, bb1, acc[0][1], 0, 0, 0);
      acc[1][0] = __builtin_amdgcn_mfma_f32_16x16x32_bf16(a1, bb0, acc[1][0], 0, 0, 0);
      acc[1][1] = __builtin_amdgcn_mfma_f32_16x16x32_bf16(a1, bb1, acc[1][1], 0, 0, 0);
    }
  };
  if constexpr (DBUF){
    int nk = K >> 6;
    LOADG(0);
    WRITEL(0);
    __syncthreads();
    for (int ki = 0; ki < nk; ki++){
      int cur = ki & 1;
      if (ki + 1 < nk) LOADG((ki + 1) << 6);
      COMPUTE(cur);
      if (ki + 1 < nk) WRITEL(cur ^ 1);
      __syncthreads();
    }
  } else {
    for (int k0 = 0; k0 < K; k0 += 64){
      __syncthreads();
      LOADG(k0);
      WRITEL(0);
      __syncthreads();
      COMPUTE(0);
    }
  }
  if constexpr (EPI == 1){
    #pragma unroll
    for (int mi = 0; mi < 2; mi++)
    #pragma unroll
    for (int ni = 0; ni < 2; ni++)
    #pragma unroll
    for (int r = 0; r < 4; r++){
      int row = bm + wm + mi * 16 + ((l >> 4) << 2) + r;
      int col = bn + wn + ni * 16 + (l & 15);
      size_t idx = (size_t)row * Nn + col;
      outf[idx] = resid[idx] + acc[mi][ni][r] + bias[col];
    }
  } else {
    // LDS-staged coalesced bf16 epilogue: scatter into As[0], read back row-contiguous.
    __syncthreads();
    u16 (*CS)[68] = As[0];
    #pragma unroll
    for (int mi = 0; mi < 2; mi++)
    #pragma unroll
    for (int ni = 0; ni < 2; ni++)
    #pragma unroll
    for (int r = 0; r < 4; r++){
      int row = wm + mi * 16 + ((l >> 4) << 2) + r;
      int col = wn + ni * 16 + (l & 15);
      float v = acc[mi][ni][r];
      if (EPI == 2){
        v += bias[bn + col];
        v = 0.5f * v * (1.0f + erff(v * 0.70710678118f));
      }
      CS[row][col] = f2bf(v);
    }
    __syncthreads();
    int row = t >> 2, c0 = (t & 3) * 16;
    uint4 v0 = *(const uint4*)&CS[row][c0];
    uint4 v1 = *(const uint4*)&CS[row][c0 + 8];
    u16* op = outb + (size_t)(bm + row) * Nn + bn + c0;
    *(uint4*)op       = v0;
    *(uint4*)(op + 8) = v1;
  }
}

// One PV k-step (16 keys): build PA frag in-register (cvt_pk + permlane32_swap), tr-read V, 3 MFMA.
#define PVSTEP(O0, O1, O2, O3, SX, BASE)                                         \
  {                                                                              \
    float p0 = __builtin_exp2f(SX[BASE + 0] - m_q);                              \
    float p1 = __builtin_exp2f(SX[BASE + 1] - m_q);                              \
    float p2 = __builtin_exp2f(SX[BASE + 2] - m_q);                              \
    float p3 = __builtin_exp2f(SX[BASE + 3] - m_q);                              \
    float p4 = __builtin_exp2f(SX[BASE + 4] - m_q);                              \
    float p5 = __builtin_exp2f(SX[BASE + 5] - m_q);                              \
    float p6 = __builtin_exp2f(SX[BASE + 6] - m_q);                              \
    float p7 = __builtin_exp2f(SX[BASE + 7] - m_q);                              \
    u32 wa0, wa1, wb0, wb1;                                                      \
    asm("v_cvt_pk_bf16_f32 %0, %1, %2" : "=v"(wa0) : "v"(p0), "v"(p1));          \
    asm("v_cvt_pk_bf16_f32 %0, %1, %2" : "=v"(wa1) : "v"(p2), "v"(p3));          \
    asm("v_cvt_pk_bf16_f32 %0, %1, %2" : "=v"(wb0) : "v"(p4), "v"(p5));          \
    asm("v_cvt_pk_bf16_f32 %0, %1, %2" : "=v"(wb1) : "v"(p6), "v"(p7));          \
    asm("v_permlane32_swap_b32 %0, %1" : "+v"(wa0), "+v"(wb0));                  \
    asm("v_permlane32_swap_b32 %0, %1" : "+v"(wa1), "+v"(wb1));                  \
    F8 pa; pa.w[0] = wa0; pa.w[1] = wa1; pa.w[2] = wb0; pa.w[3] = wb1;           \
    u64 ta, tb, tc, td;                                                          \
    asm volatile("ds_read_b64_tr_b16 %0, %4 offset:" #O0 "\n\t"                  \
                 "ds_read_b64_tr_b16 %1, %4 offset:" #O1 "\n\t"                  \
                 "ds_read_b64_tr_b16 %2, %4 offset:" #O2 "\n\t"                  \
                 "ds_read_b64_tr_b16 %3, %4 offset:" #O3 "\n\t"                  \
                 "s_waitcnt lgkmcnt(0)"                                          \
                 : "=&v"(ta), "=&v"(tb), "=&v"(tc), "=&v"(td)                    \
                 : "v"(vtr));                                                    \
    __builtin_amdgcn_sched_barrier(0);                                           \
    F8 f0, f1;                                                                   \
    f0.w[0] = (u32)ta; f0.w[1] = (u32)(ta >> 32);                                \
    f0.w[2] = (u32)tb; f0.w[3] = (u32)(tb >> 32);                                \
    f1.w[0] = (u32)tc; f1.w[1] = (u32)(tc >> 32);                                \
    f1.w[2] = (u32)td; f1.w[3] = (u32)(td >> 32);                                \
    l_acc = __builtin_amdgcn_mfma_f32_32x32x16_bf16(pa.v, onesf, l_acc, 0, 0, 0);\
    o_0 = __builtin_amdgcn_mfma_f32_32x32x16_bf16(pa.v, f0.v, o_0, 0, 0, 0);     \
    o_1 = __builtin_amdgcn_mfma_f32_32x32x16_bf16(pa.v, f1.v, o_1, 0, 0, 0);     \
  }

// MFMA flash attention: swapped QK^T (S^T = K Q^T) -> in-register softmax, no P LDS.
// Block = 256 thr (4 waves), q-tile 128 (32 q/wave), KV tile 64, KV-split 2, XCD-pinned.
__global__ __launch_bounds__(256, 3) void attn_mfma(const u16* __restrict__ qkv,
    u16* __restrict__ o0buf, u16* __restrict__ o1buf, float2* __restrict__ mlbuf){
  __shared__ u16 Ks[64][68];                               // [key][d]
  __shared__ __attribute__((aligned(128))) u16 Vs[4096];   // [key>>2][dblk][4][16] subtiled
  int t = threadIdx.x;
  int w = t >> 6, l = t & 63;
  int c31 = l & 31, hi = l >> 5, hi8 = hi * 8;
  int id = blockIdx.x;
  int xcd = id & 7, slot = id >> 3;
  int qb = slot & 15;
  int group = (slot >> 4) * 8 + xcd;
  int bh = group % (BB * NHEAD);
  int sp = group / (BB * NHEAD);
  int b = bh / NHEAD, h = bh % NHEAD;
  int q0 = qb * 128;

  const float QS = 0.1803368801111716f;                    // 0.125 * log2(e)
  bf16x8 qf[4];
  {
    const u16* qp = qkv + (size_t)(b * NNCTX + q0 + w * 32 + c31) * 1152 + h * 64 + hi8;
    #pragma unroll
    for (int c = 0; c < 4; c++){
      U8 r; r.u = *(const uint4*)(qp + c * 16);
      #pragma unroll
      for (int j = 0; j < 8; j++) r.s[j] = f2bf(bf2f(r.s[j]) * QS);
      qf[c] = r.v;
    }
  }
  bf16x8 onesf;
  {
    U8 r;
    #pragma unroll
    for (int j = 0; j < 8; j++) r.s[j] = 0x3F80;
    onesf = r.v;
  }
  f32x16 o_0 = {}, o_1 = {};
  f32x16 l_acc = {};
  float m_q = -3.4e38f;

  const size_t kvrow = (size_t)(b * NNCTX) * 1152 + h * 64;
  int kkey = t >> 2, kdp = (t & 3) * 16;
  int vkey = t & 63, vdblk = w * 16;
  int voff = (vkey >> 2) * 256 + w * 64 + (vkey & 3) * 16;
  int lg = l >> 4, lr16 = l & 15;
  u32 vtr = (u32)(uintptr_t)(&Vs[0]) + (u32)((lg >> 1) * 1024 + (lg & 1) * 128 + lr16 * 8);

  uint4 kra, krb, vra, vrb;
  auto LOADT = [&](int kt){
    const u16* kp = qkv + kvrow + (size_t)(kt * 64 + kkey) * 1152 + 384 + kdp;
    kra = *(const uint4*)kp;
    krb = *(const uint4*)(kp + 8);
    const u16* vp = qkv + kvrow + (size_t)(kt * 64 + vkey) * 1152 + 768 + vdblk;
    vra = *(const uint4*)vp;
    vrb = *(const uint4*)(vp + 8);
  };
  auto WRITET = [&](){
    *(uint4*)&Ks[kkey][kdp]     = kra;
    *(uint4*)&Ks[kkey][kdp + 8] = krb;
    *(uint4*)&Vs[voff]     = vra;
    *(uint4*)&Vs[voff + 8] = vrb;
  };

  int ktbeg = sp * 16, ktend = ktbeg + 16;
  LOADT(ktbeg);
  WRITET();
  __syncthreads();

  for (int kt = ktbeg; kt < ktend; kt++){
    if (kt + 1 < ktend) LOADT(kt + 1);

    f32x16 s0 = {}, s1 = {};
    #pragma unroll
    for (int c = 0; c < 4; c++){
      bf16x8 kf0 = *(const bf16x8*)&Ks[c31][c * 16 + hi8];
      bf16x8 kf1 = *(const bf16x8*)&Ks[32 + c31][c * 16 + hi8];
      s0 = __builtin_amdgcn_mfma_f32_32x32x16_bf16(kf0, qf[c], s0, 0, 0, 0);
      s1 = __builtin_amdgcn_mfma_f32_32x32x16_bf16(kf1, qf[c], s1, 0, 0, 0);
    }
    float px = fmaxf(s0[0], s0[1]);
    #pragma unroll
    for (int r = 2; r < 16; r++) px = fmaxf(px, s0[r]);
    #pragma unroll
    for (int r = 0; r < 16; r++) px = fmaxf(px, s1[r]);
    px = fmaxf(px, __shfl_xor(px, 32));
    if (!__all(px <= m_q + 8.f)){
      float mn = fmaxf(m_q, px);
      float a = __builtin_exp2f(m_q - mn);
      m_q = mn;
      #pragma unroll
      for (int r = 0; r < 16; r++){
        int cr = (r & 3) + 8 * (r >> 2) + 4 * hi;
        float ar = __shfl(a, cr);
        o_0[r] *= ar; o_1[r] *= ar; l_acc[r] *= ar;
      }
    }
    PVSTEP(0, 512, 256, 768, s0, 0)
    PVSTEP(2048, 2560, 2304, 2816, s0, 8)
    PVSTEP(4096, 4608, 4352, 4864, s1, 0)
    PVSTEP(6144, 6656, 6400, 6912, s1, 8)

    __syncthreads();
    if (kt + 1 < ktend) WRITET();
    __syncthreads();
  }
  u16* obuf = sp ? o1buf : o0buf;
  #pragma unroll
  for (int r = 0; r < 16; r++){
    int cr = (r & 3) + 8 * (r >> 2) + 4 * hi;
    float mr = __shfl(m_q, cr);
    int n = q0 + w * 32 + cr;
    size_t row = (size_t)(b * NNCTX + n);
    u16* op = obuf + row * CCH + h * 64;
    op[c31]      = f2bf(o_0[r]);
    op[32 + c31] = f2bf(o_1[r]);
    if (c31 == 0)
      mlbuf[((size_t)(sp * BB * NHEAD + bh)) * NNCTX + n] = make_float2(mr, l_acc[r]);
  }
}

// Merge the two KV-splits.
__global__ __launch_bounds__(128) void attn_combine(const u16* __restrict__ o0, const u16* __restrict__ o1,
    const float2* __restrict__ ml, u16* __restrict__ obuf){
  __shared__ float sc0[NHEAD], sc1[NHEAD];
  int row = blockIdx.x;
  int b = row >> 11, n = row & 2047;
  int t = threadIdx.x;
  if (t < NHEAD){
    float2 a = ml[(size_t)(b * NHEAD + t) * NNCTX + n];
    float2 c = ml[(size_t)(BB * NHEAD + b * NHEAD + t) * NNCTX + n];
    float M = fmaxf(a.x, c.x);
    float e0 = exp2f(a.x - M), e1 = exp2f(c.x - M);
    float inv = 1.0f / (a.y * e0 + c.y * e1);
    sc0[t] = e0 * inv; sc1[t] = e1 * inv;
  }
  __syncthreads();
  size_t base = (size_t)row * CCH;
  #pragma unroll
  for (int i = 0; i < 3; i++){
    int c = t + i * 128;
    int h = c >> 6;
    float v = bf2f(o0[base + c]) * sc0[h] + bf2f(o1[base + c]) * sc1[h];
    obuf[base + c] = f2bf(v);
  }
}

extern "C" void kernel_launch(void* const* d_in, const int* in_sizes, int n_in,
                              void* d_out, int out_size, void* d_ws, size_t ws_size,
                              hipStream_t stream){
  const float* x      = (const float*)d_in[0];
  const float* ln1_g  = (const float*)d_in[1];
  const float* ln1_b  = (const float*)d_in[2];
  const float* w_qkv  = (const float*)d_in[3];
  const float* w_proj = (const float*)d_in[4];
  const float* b_proj = (const float*)d_in[5];
  const float* ln2_g  = (const float*)d_in[6];
  const float* ln2_b  = (const float*)d_in[7];
  const float* w_fc1  = (const float*)d_in[8];
  const float* b_fc1  = (const float*)d_in[9];
  const float* w_fc2  = (const float*)d_in[10];
  const float* b_fc2  = (const float*)d_in[11];
  float* out = (float*)d_out;

  u16* ws = (u16*)d_ws;
  u16* wqkv_bf  = ws;                       // [1152][384] transposed
  u16* wproj_bf = wqkv_bf + 442368;         // [384][384]
  u16* wfc1_bf  = wproj_bf + 147456;        // [1536][384]
  u16* wfc2_bf  = wfc1_bf + 589824;         // [384][1536]
  u16* h_bf     = wfc2_bf + 589824;         // 8192*384 (LN out; reused as opart0, then h2)
  u16* qkv_bf   = h_bf + 3145728;           // 8192*1152
  u16* o_bf     = qkv_bf + 9437184;         // 8192*384 (combined attention out)
  u16* opart1   = o_bf + 3145728;           // 8192*384
  float2* mlbuf = (float2*)(opart1 + 3145728); // [2][B*H][N]
  u16* opart0   = h_bf;
  u16* m_bf     = qkv_bf;                   // 8192*1536 (reuses qkv+o after proj)

  cast_tr<<<432, 256, 0, stream>>>(w_qkv, w_proj, w_fc1, w_fc2, wqkv_bf, wproj_bf, wfc1_bf, wfc2_bf);

  // LN1 -> h (bf16)
  ln_kernel<<<8192, 128, 0, stream>>>(x, ln1_g, ln1_b, h_bf);
  // QKV = h @ w_qkv  (64^2 tiles, 8 blocks/CU)
  gemm_bf16<0, 0><<<dim3(18, 128), 256, 0, stream>>>(h_bf, wqkv_bf, 384, 1152, qkv_bf, nullptr, nullptr, nullptr);
  // attention (KV-split 2, XCD-pinned, in-register softmax) -> partial O + (m,l)
  attn_mfma<<<dim3(768), 256, 0, stream>>>(qkv_bf, opart0, opart1, mlbuf);
  // combine splits -> o (bf16)
  attn_combine<<<8192, 128, 0, stream>>>(opart0, opart1, mlbuf, o_bf);
  // x1 = x + o @ w_proj + b_proj
  gemm_bf16<1, 1><<<dim3(6, 128), 256, 0, stream>>>(o_bf, wproj_bf, 384, 384, nullptr, b_proj, x, out);
  // LN2 -> h2
  ln_kernel<<<8192, 128, 0, stream>>>(out, ln2_g, ln2_b, h_bf);
  // m = gelu(h2 @ w_fc1 + b_fc1)
  gemm_bf16<2, 0><<<dim3(24, 128), 256, 0, stream>>>(h_bf, wfc1_bf, 384, 1536, m_bf, b_fc1, nullptr, nullptr);
  // out = x1 + m @ w_fc2 + b_fc2
  gemm_bf16<1, 1><<<dim3(6, 128), 256, 0, stream>>>(m_bf, wfc2_bf, 1536, 384, nullptr, b_fc2, out, out);
}